// Round 6
// baseline (726.167 us; speedup 1.0000x reference)
//
#include <hip/hip_runtime.h>
#include <hip/hip_bf16.h>

typedef unsigned short u16;
typedef __bf16 bf16x8 __attribute__((ext_vector_type(8)));
typedef float f32x4 __attribute__((ext_vector_type(4)));

#define S_DIM 2048
#define B_DIM 32
#define H_DIM 1024
#define M_DIM (S_DIM * B_DIM)

__device__ __forceinline__ float fast_tanh(float x) {
  // tanh(x) = 1 - 2/(e^{2x}+1); e->inf => 1, e->0 => -1; no NaN
  float e = __expf(2.0f * x);
  return 1.0f - 2.0f * __builtin_amdgcn_rcpf(e + 1.0f);
}

// Convert W_attn[:, H:2H] (f32, row stride 2H) -> W2 bf16 [H][H] row-major
__global__ void wconv_kernel(const float* __restrict__ W, u16* __restrict__ W2) {
  const int h = blockIdx.x;
  const int t = threadIdx.x; // 256 threads, 4 floats each
  float4 w4 = *(const float4*)(W + (size_t)h * (2 * H_DIM) + H_DIM + t * 4);
  union { u16 s[4]; uint2 v; } pk;
  pk.s[0] = __builtin_bit_cast(u16, (__bf16)w4.x);
  pk.s[1] = __builtin_bit_cast(u16, (__bf16)w4.y);
  pk.s[2] = __builtin_bit_cast(u16, (__bf16)w4.z);
  pk.s[3] = __builtin_bit_cast(u16, (__bf16)w4.w);
  *(uint2*)(W2 + (size_t)h * H_DIM + t * 4) = pk.v;
}

// u_t[h][b] = dot(hidden[b,:], W_attn[h, 0:H]) + b_attn[h]   (fp32, TRANSPOSED)
__global__ void uprep_kernel(const float* __restrict__ hidden, const float* __restrict__ W,
                             const float* __restrict__ bias, float* __restrict__ u_t) {
  int t = blockIdx.x * 256 + threadIdx.x;   // 0..131071
  int h = t >> 7;
  int b = (t >> 2) & 31;
  int kq = t & 3;
  const float4* hv = (const float4*)(hidden + (size_t)b * H_DIM) + kq * 64;
  const float4* wv = (const float4*)(W + (size_t)h * (2 * H_DIM)) + kq * 64;
  float acc = 0.f;
  #pragma unroll 4
  for (int i = 0; i < 64; ++i) {
    float4 a = hv[i], w = wv[i];
    acc += a.x * w.x + a.y * w.y + a.z * w.z + a.w * w.w;
  }
  acc += __shfl_xor(acc, 1);
  acc += __shfl_xor(acc, 2);
  if (kq == 0) u_t[(size_t)h * B_DIM + b] = acc + bias[h];
}

// Fused GEMM + tanh + v-dot. Block = 64 enc rows x FULL N=1024 (enc read once).
// A-panel (64 x 1024 bf16, 128 KB) staged to LDS ONCE, k-chunk-major [kc][row]
// (R4-verified conflict-free). K-loop has ZERO barriers: A_s read-only, B (W2)
// streamed L2->regs in a 4-deep named-register pipeline. N processed serially
// in 8 chunks of 128 cols; per-chunk epilogue (tanh + v-dot) overlaps MFMA.
// 512 thr / 8 waves, wave grid 2m x 4n, wave tile 32m x 32n, acc 16 f32/thread.
__global__ __launch_bounds__(512, 2)
void gemm_kernel(const float* __restrict__ enc, const u16* __restrict__ W2,
                 const float* __restrict__ u_t, const float* __restrict__ v,
                 float* __restrict__ scores) {
  __shared__ u16 A_s[128 * 64 * 8];   // [kc 0..127][row 0..63][8 elems] = 128 KB
  __shared__ float red_s[4][64];

  const int tid  = threadIdx.x;
  const int lane = tid & 63;
  const int wid  = tid >> 6;    // 0..7
  const int wm   = wid >> 2;    // 0..1 (row half)
  const int wn   = wid & 3;     // 0..3 (32-col group within chunk)
  const int q    = lane >> 4;   // 0..3
  const int c16  = lane & 15;
  const int m0   = blockIdx.x * 64;

  // ---- prologue: stage A panel (f32 -> bf16), k-chunk-major ----
  {
    const int srow = wid * 8 + (lane >> 3);   // 0..63
    const int c8   = lane & 7;                // 0..7
    const float* ap = enc + (size_t)(m0 + srow) * H_DIM + c8 * 8;
    #pragma unroll
    for (int j = 0; j < 16; ++j) {
      float4 f0 = *(const float4*)(ap + j * 64);
      float4 f1 = *(const float4*)(ap + j * 64 + 4);
      union { u16 s[8]; uint4 v4; } pk;
      pk.s[0] = __builtin_bit_cast(u16, (__bf16)f0.x);
      pk.s[1] = __builtin_bit_cast(u16, (__bf16)f0.y);
      pk.s[2] = __builtin_bit_cast(u16, (__bf16)f0.z);
      pk.s[3] = __builtin_bit_cast(u16, (__bf16)f0.w);
      pk.s[4] = __builtin_bit_cast(u16, (__bf16)f1.x);
      pk.s[5] = __builtin_bit_cast(u16, (__bf16)f1.y);
      pk.s[6] = __builtin_bit_cast(u16, (__bf16)f1.z);
      pk.s[7] = __builtin_bit_cast(u16, (__bf16)f1.w);
      *(uint4*)&A_s[((c8 + j * 8) * 64 + srow) * 8] = pk.v4;
    }
  }

  // per-lane B base: col (wn*32 + nf*16 + c16), k-chunk q; advanced per chunk
  const u16* wchunk = W2 + (size_t)(wn * 32 + c16) * H_DIM + q * 8;

  #define LOADB(dA, dB, CH, KK)                                               \
    {                                                                         \
      const u16* p = wchunk + (CH) * 131072 + (KK) * 32;                      \
      dA = *(const bf16x8*)p;                                                 \
      dB = *(const bf16x8*)(p + 16384);                                       \
    }

  // prime 4-deep B pipeline (before barrier: overlaps staging drain)
  bf16x8 b0a, b0b, b1a, b1b, b2a, b2b, b3a, b3b;
  LOADB(b0a, b0b, 0, 0)
  LOADB(b1a, b1b, 0, 1)
  LOADB(b2a, b2b, 0, 2)
  LOADB(b3a, b3b, 0, 3)

  __syncthreads();   // the ONLY barrier before the final reduction

  const char* Abase = (const char*)A_s + q * 1024 + (wm * 32 + c16) * 16;
  f32x4 rs0 = {0.f, 0.f, 0.f, 0.f};
  f32x4 rs1 = {0.f, 0.f, 0.f, 0.f};

  #define COMPUTE(KK, ba, bb)                                                 \
    {                                                                         \
      const char* Ap = Abase + ((KK) >> 4) * 65536 + ((KK) & 15) * 4096;      \
      bf16x8 a0 = *(const bf16x8*)(Ap);                                       \
      bf16x8 a1 = *(const bf16x8*)(Ap + 256);                                 \
      acc00 = __builtin_amdgcn_mfma_f32_16x16x32_bf16(a0, ba, acc00, 0, 0, 0);\
      acc01 = __builtin_amdgcn_mfma_f32_16x16x32_bf16(a0, bb, acc01, 0, 0, 0);\
      acc10 = __builtin_amdgcn_mfma_f32_16x16x32_bf16(a1, ba, acc10, 0, 0, 0);\
      acc11 = __builtin_amdgcn_mfma_f32_16x16x32_bf16(a1, bb, acc11, 0, 0, 0);\
    }

  for (int chunk = 0; chunk < 8; ++chunk) {
    f32x4 acc00 = {0.f, 0.f, 0.f, 0.f};
    f32x4 acc01 = {0.f, 0.f, 0.f, 0.f};
    f32x4 acc10 = {0.f, 0.f, 0.f, 0.f};
    f32x4 acc11 = {0.f, 0.f, 0.f, 0.f};

    #pragma unroll
    for (int ks4 = 0; ks4 < 8; ++ks4) {
      const int kk = ks4 * 4;
      bf16x8 n0a, n0b, n1a, n1b, n2a, n2b, n3a, n3b;
      LOADB(n0a, n0b, (kk + 4) >> 5, (kk + 4) & 31)
      LOADB(n1a, n1b, (kk + 5) >> 5, (kk + 5) & 31)
      LOADB(n2a, n2b, (kk + 6) >> 5, (kk + 6) & 31)
      LOADB(n3a, n3b, (kk + 7) >> 5, (kk + 7) & 31)
      COMPUTE(kk + 0, b0a, b0b)
      COMPUTE(kk + 1, b1a, b1b)
      COMPUTE(kk + 2, b2a, b2b)
      COMPUTE(kk + 3, b3a, b3b)
      b0a = n0a; b0b = n0b; b1a = n1a; b1b = n1b;
      b2a = n2a; b2b = n2b; b3a = n3a; b3b = n3b;
    }

    // ---- per-chunk epilogue: rowsum += v[h] * tanh(acc + u[b][h]) ----
    {
      const int h0 = chunk * 128 + wn * 32 + c16;
      const int h1 = h0 + 16;
      const float v0 = v[h0], v1 = v[h1];
      const f32x4 u00 = *(const f32x4*)(u_t + (size_t)h0 * B_DIM + q * 4);
      const f32x4 u01 = *(const f32x4*)(u_t + (size_t)h0 * B_DIM + 16 + q * 4);
      const f32x4 u10 = *(const f32x4*)(u_t + (size_t)h1 * B_DIM + q * 4);
      const f32x4 u11 = *(const f32x4*)(u_t + (size_t)h1 * B_DIM + 16 + q * 4);
      #pragma unroll
      for (int r = 0; r < 4; ++r) {
        rs0[r] += v0 * fast_tanh(acc00[r] + u00[r]) + v1 * fast_tanh(acc01[r] + u10[r]);
        rs1[r] += v0 * fast_tanh(acc10[r] + u01[r]) + v1 * fast_tanh(acc11[r] + u11[r]);
      }
    }
    wchunk += 131072;   // next 128 cols
  }

  // ---- final reduction: sum over c16 lanes, then over the 4 wn-waves ----
  #pragma unroll
  for (int r = 0; r < 4; ++r) {
    float s0 = rs0[r], s1 = rs1[r];
    s0 += __shfl_xor(s0, 1); s0 += __shfl_xor(s0, 2);
    s0 += __shfl_xor(s0, 4); s0 += __shfl_xor(s0, 8);
    s1 += __shfl_xor(s1, 1); s1 += __shfl_xor(s1, 2);
    s1 += __shfl_xor(s1, 4); s1 += __shfl_xor(s1, 8);
    if (c16 == 0) {
      red_s[wn][wm * 32 + q * 4 + r]      = s0;
      red_s[wn][wm * 32 + 16 + q * 4 + r] = s1;
    }
  }
  __syncthreads();
  if (tid < 64) {
    float s = red_s[0][tid] + red_s[1][tid] + red_s[2][tid] + red_s[3][tid];
    // scores layout [b][s] for coalesced softmax reads
    scores[(size_t)(tid & 31) * S_DIM + ((m0 + tid) >> 5)] = s;
  }
  #undef LOADB
  #undef COMPUTE
}

// softmax over S per batch row b; scores[b][s]; out[b][0][s]
__global__ void softmax_kernel(const float* __restrict__ scores, float* __restrict__ out) {
  const int b = blockIdx.x;
  const int t = threadIdx.x;        // 256
  const int lane = t & 63, wid = t >> 6;
  __shared__ float redm[4], reds[4];
  float loc[8];
  float mx = -3.0e38f;
  #pragma unroll
  for (int i = 0; i < 8; ++i) {
    loc[i] = scores[(size_t)b * S_DIM + i * 256 + t];
    mx = fmaxf(mx, loc[i]);
  }
  #pragma unroll
  for (int off = 1; off < 64; off <<= 1) mx = fmaxf(mx, __shfl_xor(mx, off));
  if (lane == 0) redm[wid] = mx;
  __syncthreads();
  mx = fmaxf(fmaxf(redm[0], redm[1]), fmaxf(redm[2], redm[3]));
  float sum = 0.f;
  #pragma unroll
  for (int i = 0; i < 8; ++i) { loc[i] = __expf(loc[i] - mx); sum += loc[i]; }
  #pragma unroll
  for (int off = 1; off < 64; off <<= 1) sum += __shfl_xor(sum, off);
  if (lane == 0) reds[wid] = sum;
  __syncthreads();
  sum = reds[0] + reds[1] + reds[2] + reds[3];
  float inv = 1.0f / sum;
  #pragma unroll
  for (int i = 0; i < 8; ++i) out[(size_t)b * S_DIM + i * 256 + t] = loc[i] * inv;
}

extern "C" void kernel_launch(void* const* d_in, const int* in_sizes, int n_in,
                              void* d_out, int out_size, void* d_ws, size_t ws_size,
                              hipStream_t stream) {
  const float* hidden = (const float*)d_in[0];
  const float* enc    = (const float*)d_in[1];
  const float* W      = (const float*)d_in[2];
  const float* bias   = (const float*)d_in[3];
  const float* v      = (const float*)d_in[4];
  float* out = (float*)d_out;

  char* ws = (char*)d_ws;
  // W2 @ 0 (2 MB) + 256 KB overread pad (B pipeline tail reads past W2)
  u16*   W2     = (u16*)ws;
  float* u_t    = (float*)(ws + (2304u << 10));   // 2.25 MB: u transposed [H][B], 128 KB
  float* scores = (float*)(ws + (2560u << 10));   // 2.50 MB: [B][S], 256 KB

  wconv_kernel<<<H_DIM, 256, 0, stream>>>(W, W2);
  uprep_kernel<<<512, 256, 0, stream>>>(hidden, W, bias, u_t);
  gemm_kernel<<<M_DIM / 64, 512, 0, stream>>>(enc, W2, u_t, v, scores);
  softmax_kernel<<<B_DIM, 256, 0, stream>>>(scores, out);
}

// Round 7
// 452.589 us; speedup vs baseline: 1.6045x; 1.6045x over previous
//
#include <hip/hip_runtime.h>
#include <hip/hip_bf16.h>

typedef unsigned short u16;
typedef unsigned long long u64;
typedef __bf16 bf16x8 __attribute__((ext_vector_type(8)));
typedef float f32x4 __attribute__((ext_vector_type(4)));

#define S_DIM 2048
#define B_DIM 32
#define H_DIM 1024
#define M_DIM (S_DIM * B_DIM)
#define NKS 32          // K = 1024 in steps of 32
#define NSLICE 8        // N = 1024 in 128-col slices

__device__ __forceinline__ float fast_tanh(float x) {
  // tanh(x) = 1 - 2/(e^{2x}+1); e->inf => 1, e->0 => -1; no NaN
  float e = __expf(2.0f * x);
  return 1.0f - 2.0f * __builtin_amdgcn_rcpf(e + 1.0f);
}

__device__ __forceinline__ void gload_lds16(const void* g, void* l) {
  __builtin_amdgcn_global_load_lds(
      (const __attribute__((address_space(1))) unsigned int*)g,
      (__attribute__((address_space(3))) unsigned int*)l,
      16, 0, 0);
}

// Convert W_attn[:, H:2H] (f32, row stride 2H) -> W2 bf16 [H][H] row-major
__global__ void wconv_kernel(const float* __restrict__ W, u16* __restrict__ W2) {
  const int h = blockIdx.x;
  const int t = threadIdx.x; // 256 threads, 4 floats each
  float4 w4 = *(const float4*)(W + (size_t)h * (2 * H_DIM) + H_DIM + t * 4);
  union { u16 s[4]; uint2 v; } pk;
  pk.s[0] = __builtin_bit_cast(u16, (__bf16)w4.x);
  pk.s[1] = __builtin_bit_cast(u16, (__bf16)w4.y);
  pk.s[2] = __builtin_bit_cast(u16, (__bf16)w4.z);
  pk.s[3] = __builtin_bit_cast(u16, (__bf16)w4.w);
  *(uint2*)(W2 + (size_t)h * H_DIM + t * 4) = pk.v;
}

// u[b][h] = dot(hidden[b,:], W_attn[h, 0:H]) + b_attn[h]   (fp32)
__global__ void uprep_kernel(const float* __restrict__ hidden, const float* __restrict__ W,
                             const float* __restrict__ bias, float* __restrict__ u) {
  int t = blockIdx.x * 256 + threadIdx.x;   // 0..131071
  int h = t >> 7;
  int b = (t >> 2) & 31;
  int kq = t & 3;
  const float4* hv = (const float4*)(hidden + (size_t)b * H_DIM) + kq * 64;
  const float4* wv = (const float4*)(W + (size_t)h * (2 * H_DIM)) + kq * 64;
  float acc = 0.f;
  #pragma unroll 4
  for (int i = 0; i < 64; ++i) {
    float4 a = hv[i], w = wv[i];
    acc += a.x * w.x + a.y * w.y + a.z * w.z + a.w * w.w;
  }
  acc += __shfl_xor(acc, 1);
  acc += __shfl_xor(acc, 2);
  if (kq == 0) u[(size_t)b * H_DIM + h] = acc + bias[h];
}

// Fused GEMM + tanh + v-dot, m97-style 128x128 tile, BK=32, 256 thr / 4 waves.
// Wave grid 2x2, wave tile 64x64, acc[4][4] f32x4 = 64 AGPR.
// LDS k-chunk-major layout [q][row][8] => all ds ops 16-lane-contiguous, no
// bank conflicts, linear global_load_lds dest (no swizzle needed).
// XCD-aware grid swizzle: the 8 n-slices of one m-panel land on the SAME XCD
// (xcd = blockIdx % 8) so the A-panel is fetched from HBM once and re-read
// from that XCD's L2 by the 7 siblings.
// Partial scores per n-slice -> partial[nb][b][s]; summed in softmax kernel.
__global__ __launch_bounds__(256, 2)
void gemm_kernel(const float* __restrict__ enc, const u16* __restrict__ W2,
                 const float* __restrict__ u, const float* __restrict__ v,
                 float* __restrict__ partial) {
  __shared__ u16 A_s[2][4096];      // [buf][(q*128+row)*8]
  __shared__ u16 B_s[2][4096];      // [buf][(q*128+col)*8]
  __shared__ float u_s[32 * 132];   // u[b][n0+h'], padded rows
  __shared__ float red_s[2][128];

  const int tid  = threadIdx.x;
  const int lane = tid & 63;
  const int wid  = tid >> 6;    // 0..3
  const int wm   = wid >> 1;    // 0..1
  const int wn   = wid & 1;     // 0..1
  const int q    = lane >> 4;   // 0..3
  const int c16  = lane & 15;

  // XCD-aware swizzle (bijective on 4096 blocks): hardware xcd = blockIdx%8.
  // mb = (b&7) + 8*(b>>6) -> all blocks of one m-panel share b&7 == same XCD;
  // nb = (b>>3)&7 enumerates the panel's 8 n-slices within that XCD.
  const int bswz = blockIdx.x;
  const int mb   = (bswz & 7) + 8 * (bswz >> 6);
  const int nb   = (bswz >> 3) & 7;
  const int m0   = mb * 128;
  const int n0   = nb * 128;

  f32x4 acc[4][4];
  #pragma unroll
  for (int mi = 0; mi < 4; ++mi)
    #pragma unroll
    for (int nf = 0; nf < 4; ++nf) {
      f32x4 z = {0.f, 0.f, 0.f, 0.f};
      acc[mi][nf] = z;
    }

  // ---- stage u slice [32][128] into padded LDS ----
  #pragma unroll
  for (int jj = 0; jj < 4; ++jj) {
    const int i  = jj * 1024 + tid * 4;
    const int b_ = i >> 7, hp = i & 127;
    float4 uv4 = *(const float4*)(u + (size_t)b_ * H_DIM + n0 + hp);
    *(float4*)&u_s[b_ * 132 + hp] = uv4;
  }

  // B staging: 512 slots of 16B; slot = q*128+col; linear dest, per-lane src.
  #define STAGE_B(buf, ks)                                                    \
    {                                                                         \
      _Pragma("unroll")                                                       \
      for (int j = 0; j < 2; ++j) {                                           \
        const int slot = j * 256 + tid;                                       \
        gload_lds16(W2 + (size_t)(n0 + (slot & 127)) * H_DIM + (ks) * 32 +    \
                        (slot >> 7) * 8,                                      \
                    &B_s[buf][slot * 8]);                                     \
      }                                                                       \
    }

  #define PACK_WRITE_A(buf, AF)                                               \
    {                                                                         \
      _Pragma("unroll")                                                       \
      for (int j = 0; j < 2; ++j) {                                           \
        union { u16 s[8]; uint4 vv; } pk;                                     \
        pk.s[0] = __builtin_bit_cast(u16, (__bf16)AF[j][0].x);                \
        pk.s[1] = __builtin_bit_cast(u16, (__bf16)AF[j][0].y);                \
        pk.s[2] = __builtin_bit_cast(u16, (__bf16)AF[j][0].z);                \
        pk.s[3] = __builtin_bit_cast(u16, (__bf16)AF[j][0].w);                \
        pk.s[4] = __builtin_bit_cast(u16, (__bf16)AF[j][1].x);                \
        pk.s[5] = __builtin_bit_cast(u16, (__bf16)AF[j][1].y);                \
        pk.s[6] = __builtin_bit_cast(u16, (__bf16)AF[j][1].z);                \
        pk.s[7] = __builtin_bit_cast(u16, (__bf16)AF[j][1].w);                \
        *(uint4*)&A_s[buf][(j * 256 + tid) * 8] = pk.vv;                      \
      }                                                                       \
    }

  #define LOAD_A(AF, ks)                                                      \
    {                                                                         \
      _Pragma("unroll")                                                       \
      for (int j = 0; j < 2; ++j) {                                           \
        const int task = j * 256 + tid;                                       \
        const float* ap = enc + (size_t)(m0 + (task & 127)) * H_DIM +         \
                          (ks) * 32 + (task >> 7) * 8;                        \
        AF[j][0] = *(const float4*)ap;                                        \
        AF[j][1] = *(const float4*)(ap + 4);                                  \
      }                                                                       \
    }

  // ---- prologue: stage ks=0 ----
  STAGE_B(0, 0);
  {
    float4 af[2][2];
    LOAD_A(af, 0);
    PACK_WRITE_A(0, af);
  }
  __syncthreads();

  // ---- K loop: one barrier per ks; issue next-ks loads before MFMA ----
  #define KSTEP(ks, CUR)                                                      \
    {                                                                         \
      float4 af[2][2];                                                        \
      const bool pf = (ks) + 1 < NKS;                                         \
      if (pf) {                                                               \
        STAGE_B((CUR) ^ 1, (ks) + 1);                                         \
        LOAD_A(af, (ks) + 1);                                                 \
      }                                                                       \
      bf16x8 a[4], b[4];                                                      \
      _Pragma("unroll")                                                       \
      for (int mi = 0; mi < 4; ++mi)                                          \
        a[mi] = *(const bf16x8*)&A_s[CUR][(q * 128 + wm * 64 + mi * 16 + c16) * 8]; \
      _Pragma("unroll")                                                       \
      for (int nf = 0; nf < 4; ++nf)                                          \
        b[nf] = *(const bf16x8*)&B_s[CUR][(q * 128 + wn * 64 + nf * 16 + c16) * 8]; \
      _Pragma("unroll")                                                       \
      for (int nf = 0; nf < 4; ++nf)                                          \
        _Pragma("unroll")                                                     \
        for (int mi = 0; mi < 4; ++mi)                                        \
          acc[mi][nf] = __builtin_amdgcn_mfma_f32_16x16x32_bf16(              \
              a[mi], b[nf], acc[mi][nf], 0, 0, 0);                            \
      if (pf) PACK_WRITE_A((CUR) ^ 1, af);                                    \
      __syncthreads();                                                        \
    }

  for (int k2 = 0; k2 < NKS / 2; ++k2) {
    KSTEP(2 * k2, 0);
    KSTEP(2 * k2 + 1, 1);
  }

  // ---- epilogue: rowsum over this block's 128 cols ----
  float vv[4];
  #pragma unroll
  for (int nf = 0; nf < 4; ++nf)
    vv[nf] = v[n0 + wn * 64 + nf * 16 + c16];

  float rowsum[4][4];
  #pragma unroll
  for (int mi = 0; mi < 4; ++mi)
    #pragma unroll
    for (int r = 0; r < 4; ++r) rowsum[mi][r] = 0.f;

  #pragma unroll
  for (int nf = 0; nf < 4; ++nf) {
    const int hp = wn * 64 + nf * 16 + c16;
    #pragma unroll
    for (int mi = 0; mi < 4; ++mi)
      #pragma unroll
      for (int r = 0; r < 4; ++r) {
        const int b_ = (mi * 16 + q * 4 + r) & 31;   // row mod 32 (wm*64 ≡ 0)
        float x = acc[mi][nf][r] + u_s[b_ * 132 + hp];
        rowsum[mi][r] += vv[nf] * fast_tanh(x);
      }
  }
  #pragma unroll
  for (int mi = 0; mi < 4; ++mi)
    #pragma unroll
    for (int r = 0; r < 4; ++r) {
      float s = rowsum[mi][r];
      s += __shfl_xor(s, 1);
      s += __shfl_xor(s, 2);
      s += __shfl_xor(s, 4);
      s += __shfl_xor(s, 8);
      if (c16 == 0) red_s[wn][wm * 64 + mi * 16 + q * 4 + r] = s;
    }
  __syncthreads();
  if (tid < 128) {
    const float sres = red_s[0][tid] + red_s[1][tid];
    const int b_ = tid & 31;
    const int s_ = (m0 + tid) >> 5;
    partial[(size_t)nb * M_DIM + (size_t)b_ * S_DIM + s_] = sres;
  }
  #undef STAGE_B
  #undef PACK_WRITE_A
  #undef LOAD_A
  #undef KSTEP
}

// softmax over S per batch row b, fused with the 8-slice partial reduction.
// partial layout: [nb][b][s]; out[b][0][s].
__global__ void softmax_kernel(const float* __restrict__ partial, float* __restrict__ out) {
  const int b = blockIdx.x;
  const int t = threadIdx.x;        // 256
  const int lane = t & 63, wid = t >> 6;
  __shared__ float redm[4], reds[4];
  float loc[8];
  float mx = -3.0e38f;
  #pragma unroll
  for (int i = 0; i < 8; ++i) {
    const int s = i * 256 + t;
    float a = 0.f;
    #pragma unroll
    for (int j = 0; j < NSLICE; ++j)
      a += partial[(size_t)j * M_DIM + (size_t)b * S_DIM + s];
    loc[i] = a;
    mx = fmaxf(mx, a);
  }
  #pragma unroll
  for (int off = 1; off < 64; off <<= 1) mx = fmaxf(mx, __shfl_xor(mx, off));
  if (lane == 0) redm[wid] = mx;
  __syncthreads();
  mx = fmaxf(fmaxf(redm[0], redm[1]), fmaxf(redm[2], redm[3]));
  float sum = 0.f;
  #pragma unroll
  for (int i = 0; i < 8; ++i) { loc[i] = __expf(loc[i] - mx); sum += loc[i]; }
  #pragma unroll
  for (int off = 1; off < 64; off <<= 1) sum += __shfl_xor(sum, off);
  if (lane == 0) reds[wid] = sum;
  __syncthreads();
  sum = reds[0] + reds[1] + reds[2] + reds[3];
  float inv = 1.0f / sum;
  #pragma unroll
  for (int i = 0; i < 8; ++i) out[(size_t)b * S_DIM + i * 256 + t] = loc[i] * inv;
}

extern "C" void kernel_launch(void* const* d_in, const int* in_sizes, int n_in,
                              void* d_out, int out_size, void* d_ws, size_t ws_size,
                              hipStream_t stream) {
  const float* hidden = (const float*)d_in[0];
  const float* enc    = (const float*)d_in[1];
  const float* W      = (const float*)d_in[2];
  const float* bias   = (const float*)d_in[3];
  const float* v      = (const float*)d_in[4];
  float* out = (float*)d_out;

  char* ws = (char*)d_ws;
  u16*   W2      = (u16*)ws;                                       // 2 MB
  float* u       = (float*)(ws + (2u << 20));                      // 128 KB
  float* partial = (float*)(ws + (2u << 20) + (128u << 10));       // 2 MB

  wconv_kernel<<<H_DIM, 256, 0, stream>>>(W, W2);
  uprep_kernel<<<512, 256, 0, stream>>>(hidden, W, bias, u);
  gemm_kernel<<<(M_DIM / 128) * NSLICE, 256, 0, stream>>>(enc, W2, u, v, partial);
  softmax_kernel<<<B_DIM, 256, 0, stream>>>(partial, out);
}